// Round 1
// baseline (496.983 us; speedup 1.0000x reference)
//
#include <hip/hip_runtime.h>

#define D 128
#define NG 128
#define NBINS 64

// ---------- degree histogram over dst ----------
__global__ __launch_bounds__(256) void k_hist(const int* __restrict__ dst, int E, int* __restrict__ deg) {
    int i = blockIdx.x * 256 + threadIdx.x;
    if (i < E) atomicAdd(&deg[dst[i]], 1);
}

// ---------- per-graph node counts via binary search (batch is sorted) ----------
__global__ __launch_bounds__(128) void k_cnt(const int* __restrict__ batch, int N, int* __restrict__ cnt) {
    int g = threadIdx.x;  // 0..127
    int lo = 0, hi = N;
    while (lo < hi) { int mid = (lo + hi) >> 1; if (batch[mid] < g) lo = mid + 1; else hi = mid; }
    int a = lo;
    hi = N;
    while (lo < hi) { int mid = (lo + hi) >> 1; if (batch[mid] < g + 1) lo = mid + 1; else hi = mid; }
    cnt[g] = lo - a;
}

// ---------- 3-kernel exclusive scan of deg -> row_start (and cursor copy) ----------
__global__ __launch_bounds__(1024) void k_scan1(const int* __restrict__ deg, int N,
                                                int* __restrict__ rs, int* __restrict__ bsum) {
    __shared__ int s[1024];
    int tid = threadIdx.x;
    int i = blockIdx.x * 1024 + tid;
    int v = (i < N) ? deg[i] : 0;
    s[tid] = v;
    __syncthreads();
    for (int off = 1; off < 1024; off <<= 1) {
        int t = (tid >= off) ? s[tid - off] : 0;
        __syncthreads();
        s[tid] += t;
        __syncthreads();
    }
    if (i < N) rs[i] = s[tid] - v;              // exclusive within block
    if (tid == 1023) bsum[blockIdx.x] = s[1023]; // block total
}

__global__ __launch_bounds__(1024) void k_scan2(int* __restrict__ bsum, int nb) {
    __shared__ int s[1024];
    int tid = threadIdx.x;
    int v = (tid < nb) ? bsum[tid] : 0;
    s[tid] = v;
    __syncthreads();
    for (int off = 1; off < 1024; off <<= 1) {
        int t = (tid >= off) ? s[tid - off] : 0;
        __syncthreads();
        s[tid] += t;
        __syncthreads();
    }
    if (tid < nb) bsum[tid] = s[tid] - v;        // exclusive block offsets
}

__global__ __launch_bounds__(1024) void k_scan3(int* __restrict__ rs, int* __restrict__ cur,
                                                const int* __restrict__ bsum, int N) {
    int i = blockIdx.x * 1024 + threadIdx.x;
    if (i < N) {
        int r = rs[i] + bsum[blockIdx.x];
        rs[i] = r;
        cur[i] = r;
    }
}

// ---------- CSR fill: csr[pos] = src for each (src,dst) edge, bucketed by dst ----------
__global__ __launch_bounds__(256) void k_fill(const int* __restrict__ src, const int* __restrict__ dst, int E,
                                              int* __restrict__ cur, int* __restrict__ csr) {
    int i = blockIdx.x * 256 + threadIdx.x;
    if (i < E) {
        int pos = atomicAdd(&cur[dst[i]], 1);
        csr[pos] = src[i];
    }
}

// ---------- GEMM: h[r][c] = dinv[r] * sum_k x[r][k]*W[k][c]   (dinv = rsqrt(deg+1)) ----------
// Tile: 64 rows x 64 cols per block (grid.y=2 col-halves). 256 threads = 16 rowgroups x 16 colgroups,
// each thread 4 rows x 4 cols. LDS: xs 64x132 (pad -> 2-way-free banks) + Ws 64x68, ~51 KB -> 3 blocks/CU.
__global__ __launch_bounds__(256) void k_gemm(const float* __restrict__ x, const float* __restrict__ W,
                                              const int* __restrict__ deg, float* __restrict__ h, int N) {
    __shared__ float xs[64][132];
    __shared__ float Ws[64][68];
    const int tid = threadIdx.x;
    const int row0 = blockIdx.x * 64;
    const int col0 = blockIdx.y * 64;
    const int rg = tid >> 4;   // 0..15
    const int cg = tid & 15;   // 0..15

    // stage x tile: 64 rows x 128 k, float4 loads (coalesced: consecutive lanes -> consecutive k-quads)
#pragma unroll
    for (int it = 0; it < 8; ++it) {
        int f = it * 256 + tid;      // float4 index, 2048 total
        int r = f >> 5;              // 0..63
        int kq = f & 31;             // 0..31
        float4 v = make_float4(0.f, 0.f, 0.f, 0.f);
        if (row0 + r < N) v = *(const float4*)&x[(size_t)(row0 + r) * D + kq * 4];
        *(float4*)&xs[r][kq * 4] = v;
    }

    float4 acc[4];
    acc[0] = acc[1] = acc[2] = acc[3] = make_float4(0.f, 0.f, 0.f, 0.f);

    for (int kb = 0; kb < 2; ++kb) {
        __syncthreads();  // xs ready (kb=0) / previous Ws consumed (kb=1)
#pragma unroll
        for (int it = 0; it < 4; ++it) {
            int f = it * 256 + tid;  // float4 index, 1024 total
            int wr = f >> 4;         // 0..63
            int wc = f & 15;         // 0..15
            *(float4*)&Ws[wr][wc * 4] = *(const float4*)&W[(size_t)(kb * 64 + wr) * D + col0 + wc * 4];
        }
        __syncthreads();
#pragma unroll 8
        for (int k = 0; k < 64; ++k) {
            float4 wv = *(float4*)&Ws[k][cg * 4];
#pragma unroll
            for (int i = 0; i < 4; ++i) {
                float xv = xs[rg * 4 + i][kb * 64 + k];
                acc[i].x += xv * wv.x;
                acc[i].y += xv * wv.y;
                acc[i].z += xv * wv.z;
                acc[i].w += xv * wv.w;
            }
        }
    }

#pragma unroll
    for (int i = 0; i < 4; ++i) {
        int r = row0 + rg * 4 + i;
        if (r < N) {
            float di = rsqrtf((float)(deg[r] + 1));
            float4 o = acc[i];
            o.x *= di; o.y *= di; o.z *= di; o.w *= di;
            *(float4*)&h[(size_t)r * D + col0 + cg * 4] = o;
        }
    }
}

// ---------- gather + finalize: one wave per node ----------
// out_row = dinv[i]*(sum_{src->i} h[src] + h[i]) + b ; PReLU ; L2 normalize ; atomic into pool bin
__global__ __launch_bounds__(256) void k_gather(const float* __restrict__ h, const int* __restrict__ rs,
                                                const int* __restrict__ deg, const int* __restrict__ csr,
                                                const int* __restrict__ batch, const float* __restrict__ b,
                                                const float* __restrict__ pa, float* __restrict__ pool, int N) {
    int node = (int)((blockIdx.x * (unsigned)blockDim.x + threadIdx.x) >> 6);
    int lane = threadIdx.x & 63;
    if (node >= N) return;

    float2 acc = *(const float2*)&h[(size_t)node * D + lane * 2];  // self-loop term
    int start = rs[node];
    int len = deg[node];
    for (int o = 0; o < len; o += 64) {
        int m = len - o;
        if (m > 64) m = 64;
        int idx = (o + lane < len) ? csr[start + o + lane] : 0;
        for (int j = 0; j < m; ++j) {
            int s = __shfl(idx, j);
            float2 v = *(const float2*)&h[(size_t)s * D + lane * 2];
            acc.x += v.x;
            acc.y += v.y;
        }
    }
    float di = rsqrtf((float)(len + 1));
    float2 bb = *(const float2*)&b[lane * 2];
    float2 aa = *(const float2*)&pa[lane * 2];
    float vx = acc.x * di + bb.x;
    float vy = acc.y * di + bb.y;
    vx = vx > 0.f ? vx : aa.x * vx;
    vy = vy > 0.f ? vy : aa.y * vy;
    float ss = vx * vx + vy * vy;
#pragma unroll
    for (int o = 32; o > 0; o >>= 1) ss += __shfl_xor(ss, o);
    float inv = 1.0f / fmaxf(sqrtf(ss), 1e-12f);
    vx *= inv;
    vy *= inv;
    int g = batch[node];
    float* p = pool + (size_t)(blockIdx.x & (NBINS - 1)) * (NG * D) + (size_t)g * D + lane * 2;
    atomicAdd(p, vx);
    atomicAdd(p + 1, vy);
}

// ---------- pool reduction: sum bins, divide by count ----------
__global__ __launch_bounds__(256) void k_pool(const float* __restrict__ pool, const int* __restrict__ cnt,
                                              float* __restrict__ out) {
    int idx = blockIdx.x * 256 + threadIdx.x;  // 0..16383
    float s = 0.f;
    for (int bin = 0; bin < NBINS; ++bin) s += pool[(size_t)bin * NG * D + idx];
    out[idx] = s / fmaxf((float)cnt[idx >> 7], 1.0f);
}

extern "C" void kernel_launch(void* const* d_in, const int* in_sizes, int n_in,
                              void* d_out, int out_size, void* d_ws, size_t ws_size,
                              hipStream_t stream) {
    const float* x = (const float*)d_in[0];
    const int* ei = (const int*)d_in[1];
    const int* batch = (const int*)d_in[2];
    const float* W = (const float*)d_in[3];
    const float* b = (const float*)d_in[4];
    const float* pa = (const float*)d_in[5];
    float* out = (float*)d_out;

    const int N = in_sizes[0] / D;
    const int E = in_sizes[1] / 2;
    const int* src = ei;
    const int* dst = ei + E;

    // carve workspace (256B-aligned chunks)
    char* w = (char*)d_ws;
    auto carve = [&](size_t bytes) {
        void* p = (void*)w;
        w += (bytes + 255) & ~(size_t)255;
        return p;
    };
    float* h = (float*)carve((size_t)N * D * sizeof(float));     // 51.2 MB
    int* deg = (int*)carve((size_t)N * sizeof(int));
    int* rs = (int*)carve((size_t)N * sizeof(int));
    int* cur = (int*)carve((size_t)N * sizeof(int));
    int* csr = (int*)carve((size_t)E * sizeof(int));             // 6.4 MB
    int* bsum = (int*)carve(1024 * sizeof(int));
    int* cnt = (int*)carve(NG * sizeof(int));
    float* pool = (float*)carve((size_t)NBINS * NG * D * sizeof(float));  // 4 MB

    hipMemsetAsync(deg, 0, (size_t)N * sizeof(int), stream);
    hipMemsetAsync(pool, 0, (size_t)NBINS * NG * D * sizeof(float), stream);

    const int nb_scan = (N + 1023) / 1024;

    k_hist<<<(E + 255) / 256, 256, 0, stream>>>(dst, E, deg);
    k_cnt<<<1, 128, 0, stream>>>(batch, N, cnt);
    k_scan1<<<nb_scan, 1024, 0, stream>>>(deg, N, rs, bsum);
    k_scan2<<<1, 1024, 0, stream>>>(bsum, nb_scan);
    k_scan3<<<nb_scan, 1024, 0, stream>>>(rs, cur, bsum, N);
    k_gemm<<<dim3((N + 63) / 64, 2), 256, 0, stream>>>(x, W, deg, h, N);
    k_fill<<<(E + 255) / 256, 256, 0, stream>>>(src, dst, E, cur, csr);
    k_gather<<<(N + 3) / 4, 256, 0, stream>>>(h, rs, deg, csr, batch, b, pa, pool, N);
    k_pool<<<NG * D / 256, 256, 0, stream>>>(pool, cnt, out);
}

// Round 2
// 461.656 us; speedup vs baseline: 1.0765x; 1.0765x over previous
//
#include <hip/hip_runtime.h>

#define D 128
#define NG 128
#define NBINS 64

typedef unsigned short ushort_t;
typedef __bf16 bf16x8 __attribute__((ext_vector_type(8)));
typedef float floatx4 __attribute__((ext_vector_type(4)));

static __device__ __forceinline__ unsigned short f2bf(float f) {
    unsigned u = __float_as_uint(f);
    unsigned r = (u + 0x7fffu + ((u >> 16) & 1u)) >> 16;  // RNE
    return (unsigned short)r;
}

// ---------- degree histogram over dst ----------
__global__ __launch_bounds__(256) void k_hist(const int* __restrict__ dst, int E, int* __restrict__ deg) {
    int i = blockIdx.x * 256 + threadIdx.x;
    if (i < E) atomicAdd(&deg[dst[i]], 1);
}

// ---------- per-graph node counts via binary search (batch is sorted) ----------
__global__ __launch_bounds__(128) void k_cnt(const int* __restrict__ batch, int N, int* __restrict__ cnt) {
    int g = threadIdx.x;
    int lo = 0, hi = N;
    while (lo < hi) { int mid = (lo + hi) >> 1; if (batch[mid] < g) lo = mid + 1; else hi = mid; }
    int a = lo;
    hi = N;
    while (lo < hi) { int mid = (lo + hi) >> 1; if (batch[mid] < g + 1) lo = mid + 1; else hi = mid; }
    cnt[g] = lo - a;
}

// ---------- 3-kernel exclusive scan of deg -> row_start (and cursor copy) ----------
__global__ __launch_bounds__(1024) void k_scan1(const int* __restrict__ deg, int N,
                                                int* __restrict__ rs, int* __restrict__ bsum) {
    __shared__ int s[1024];
    int tid = threadIdx.x;
    int i = blockIdx.x * 1024 + tid;
    int v = (i < N) ? deg[i] : 0;
    s[tid] = v;
    __syncthreads();
    for (int off = 1; off < 1024; off <<= 1) {
        int t = (tid >= off) ? s[tid - off] : 0;
        __syncthreads();
        s[tid] += t;
        __syncthreads();
    }
    if (i < N) rs[i] = s[tid] - v;
    if (tid == 1023) bsum[blockIdx.x] = s[1023];
}

__global__ __launch_bounds__(1024) void k_scan2(int* __restrict__ bsum, int nb) {
    __shared__ int s[1024];
    int tid = threadIdx.x;
    int v = (tid < nb) ? bsum[tid] : 0;
    s[tid] = v;
    __syncthreads();
    for (int off = 1; off < 1024; off <<= 1) {
        int t = (tid >= off) ? s[tid - off] : 0;
        __syncthreads();
        s[tid] += t;
        __syncthreads();
    }
    if (tid < nb) bsum[tid] = s[tid] - v;
}

__global__ __launch_bounds__(1024) void k_scan3(int* __restrict__ rs, int* __restrict__ cur,
                                                const int* __restrict__ bsum, int N) {
    int i = blockIdx.x * 1024 + threadIdx.x;
    if (i < N) {
        int r = rs[i] + bsum[blockIdx.x];
        rs[i] = r;
        cur[i] = r;
    }
}

// ---------- CSR fill ----------
__global__ __launch_bounds__(256) void k_fill(const int* __restrict__ src, const int* __restrict__ dst, int E,
                                              int* __restrict__ cur, int* __restrict__ csr) {
    int i = blockIdx.x * 256 + threadIdx.x;
    if (i < E) {
        int pos = atomicAdd(&cur[dst[i]], 1);
        csr[pos] = src[i];
    }
}

// ---------- pack W: fp32 [k][c] -> bf16 col-major Wp[c][k] ----------
__global__ __launch_bounds__(256) void k_packW(const float* __restrict__ W, ushort_t* __restrict__ Wp) {
    int t = blockIdx.x * 256 + threadIdx.x;  // 0..16383
    int c = t >> 7, k = t & 127;
    Wp[t] = f2bf(W[k * D + c]);
}

// ---------- MFMA GEMM: h[r][c] = bf16( dinv[r] * sum_k x[r][k]*W[k][c] ) ----------
// 64 rows/block, 4 waves (wave w -> rows w*16..w*16+15), full 128 cols per wave.
// A from global x (fp32->bf16 in-register), B from pre-packed Wp (L1/L2-hot, no LDS).
__global__ __launch_bounds__(256) void k_gemm(const float* __restrict__ x, const ushort_t* __restrict__ Wp,
                                              const int* __restrict__ deg, ushort_t* __restrict__ h, int N) {
    __shared__ ushort_t hs[64][130];  // transpose buffer for coalesced bf16 writes
    const int tid = threadIdx.x;
    const int w = tid >> 6;          // wave 0..3
    const int lane = tid & 63;
    const int q = lane >> 4;         // quad 0..3
    const int m = lane & 15;
    const int row0 = blockIdx.x * 64;
    const int arow = row0 + w * 16 + m;  // this lane's A row

    floatx4 acc[8];
#pragma unroll
    for (int nt = 0; nt < 8; ++nt) acc[nt] = (floatx4){0.f, 0.f, 0.f, 0.f};

    const bool rowok = (arow < N);
    const float* xrow = x + (size_t)arow * D;

#pragma unroll
    for (int kb = 0; kb < 4; ++kb) {
        // A-frag: A[m][kb*32 + q*8 + j], j=0..7
        union { bf16x8 v; ushort_t u[8]; } af;
        if (rowok) {
            float4 v0 = *(const float4*)&xrow[kb * 32 + q * 8];
            float4 v1 = *(const float4*)&xrow[kb * 32 + q * 8 + 4];
            af.u[0] = f2bf(v0.x); af.u[1] = f2bf(v0.y); af.u[2] = f2bf(v0.z); af.u[3] = f2bf(v0.w);
            af.u[4] = f2bf(v1.x); af.u[5] = f2bf(v1.y); af.u[6] = f2bf(v1.z); af.u[7] = f2bf(v1.w);
        } else {
#pragma unroll
            for (int j = 0; j < 8; ++j) af.u[j] = 0;
        }
#pragma unroll
        for (int nt = 0; nt < 8; ++nt) {
            int c = nt * 16 + m;
            const bf16x8 bf = *(const bf16x8*)(Wp + (size_t)c * D + kb * 32 + q * 8);
            acc[nt] = __builtin_amdgcn_mfma_f32_16x16x32_bf16(af.v, bf, acc[nt], 0, 0, 0);
        }
    }

    // epilogue: scale by dinv(row), bf16, LDS transpose, coalesced store
    float di[4];
#pragma unroll
    for (int r = 0; r < 4; ++r) {
        int row = row0 + w * 16 + q * 4 + r;
        di[r] = (row < N) ? rsqrtf((float)(deg[row] + 1)) : 0.f;
    }
#pragma unroll
    for (int nt = 0; nt < 8; ++nt) {
        int c = nt * 16 + m;
#pragma unroll
        for (int r = 0; r < 4; ++r) {
            hs[w * 16 + q * 4 + r][c] = f2bf(acc[nt][r] * di[r]);
        }
    }
    __syncthreads();
#pragma unroll
    for (int it = 0; it < 8; ++it) {
        int f = it * 256 + tid;      // 0..2047
        int r = f >> 5;              // 0..63
        int cq = f & 31;             // col-quad
        int row = row0 + r;
        if (row < N) {
            const ushort_t* p = &hs[r][cq * 4];
            uint2 v;
            v.x = (unsigned)p[0] | ((unsigned)p[1] << 16);
            v.y = (unsigned)p[2] | ((unsigned)p[3] << 16);
            *(uint2*)&h[(size_t)row * D + cq * 4] = v;
        }
    }
}

// ---------- gather + finalize: one wave per node, h in bf16 ----------
__global__ __launch_bounds__(256) void k_gather(const ushort_t* __restrict__ h, const int* __restrict__ rs,
                                                const int* __restrict__ deg, const int* __restrict__ csr,
                                                const int* __restrict__ batch, const float* __restrict__ b,
                                                const float* __restrict__ pa, float* __restrict__ pool, int N) {
    int node = (int)((blockIdx.x * (unsigned)blockDim.x + threadIdx.x) >> 6);
    int lane = threadIdx.x & 63;
    if (node >= N) return;

    // lane covers features 2*lane (low ushort) and 2*lane+1 (high ushort)
    unsigned sv = *(const unsigned*)&h[(size_t)node * D + lane * 2];
    float accx = __uint_as_float(sv << 16);
    float accy = __uint_as_float(sv & 0xffff0000u);

    int start = rs[node];
    int len = deg[node];
    for (int o = 0; o < len; o += 64) {
        int m = len - o;
        if (m > 64) m = 64;
        int idx = (o + lane < len) ? csr[start + o + lane] : 0;
        int j = 0;
        for (; j + 1 < m; j += 2) {
            int s0 = __shfl(idx, j);
            int s1 = __shfl(idx, j + 1);
            unsigned v0 = *(const unsigned*)&h[(size_t)s0 * D + lane * 2];
            unsigned v1 = *(const unsigned*)&h[(size_t)s1 * D + lane * 2];
            accx += __uint_as_float(v0 << 16);
            accy += __uint_as_float(v0 & 0xffff0000u);
            accx += __uint_as_float(v1 << 16);
            accy += __uint_as_float(v1 & 0xffff0000u);
        }
        if (j < m) {
            int s0 = __shfl(idx, j);
            unsigned v0 = *(const unsigned*)&h[(size_t)s0 * D + lane * 2];
            accx += __uint_as_float(v0 << 16);
            accy += __uint_as_float(v0 & 0xffff0000u);
        }
    }
    float dinv = rsqrtf((float)(len + 1));
    float2 bb = *(const float2*)&b[lane * 2];
    float2 aa = *(const float2*)&pa[lane * 2];
    float vx = accx * dinv + bb.x;
    float vy = accy * dinv + bb.y;
    vx = vx > 0.f ? vx : aa.x * vx;
    vy = vy > 0.f ? vy : aa.y * vy;
    float ss = vx * vx + vy * vy;
#pragma unroll
    for (int o = 32; o > 0; o >>= 1) ss += __shfl_xor(ss, o);
    float inv = 1.0f / fmaxf(sqrtf(ss), 1e-12f);
    vx *= inv;
    vy *= inv;
    int g = batch[node];
    float* p = pool + (size_t)(blockIdx.x & (NBINS - 1)) * (NG * D) + (size_t)g * D + lane * 2;
    atomicAdd(p, vx);
    atomicAdd(p + 1, vy);
}

// ---------- pool reduction ----------
__global__ __launch_bounds__(256) void k_pool(const float* __restrict__ pool, const int* __restrict__ cnt,
                                              float* __restrict__ out) {
    int idx = blockIdx.x * 256 + threadIdx.x;
    float s = 0.f;
    for (int bin = 0; bin < NBINS; ++bin) s += pool[(size_t)bin * NG * D + idx];
    out[idx] = s / fmaxf((float)cnt[idx >> 7], 1.0f);
}

extern "C" void kernel_launch(void* const* d_in, const int* in_sizes, int n_in,
                              void* d_out, int out_size, void* d_ws, size_t ws_size,
                              hipStream_t stream) {
    const float* x = (const float*)d_in[0];
    const int* ei = (const int*)d_in[1];
    const int* batch = (const int*)d_in[2];
    const float* W = (const float*)d_in[3];
    const float* b = (const float*)d_in[4];
    const float* pa = (const float*)d_in[5];
    float* out = (float*)d_out;

    const int N = in_sizes[0] / D;
    const int E = in_sizes[1] / 2;
    const int* src = ei;
    const int* dst = ei + E;

    char* w = (char*)d_ws;
    auto carve = [&](size_t bytes) {
        void* p = (void*)w;
        w += (bytes + 255) & ~(size_t)255;
        return p;
    };
    ushort_t* h = (ushort_t*)carve((size_t)N * D * sizeof(ushort_t));  // 25.6 MB
    ushort_t* Wp = (ushort_t*)carve((size_t)D * D * sizeof(ushort_t)); // 32 KB
    int* deg = (int*)carve((size_t)N * sizeof(int));
    int* rs = (int*)carve((size_t)N * sizeof(int));
    int* cur = (int*)carve((size_t)N * sizeof(int));
    int* csr = (int*)carve((size_t)E * sizeof(int));
    int* bsum = (int*)carve(1024 * sizeof(int));
    int* cnt = (int*)carve(NG * sizeof(int));
    float* pool = (float*)carve((size_t)NBINS * NG * D * sizeof(float));

    hipMemsetAsync(deg, 0, (size_t)N * sizeof(int), stream);
    hipMemsetAsync(pool, 0, (size_t)NBINS * NG * D * sizeof(float), stream);

    const int nb_scan = (N + 1023) / 1024;

    k_hist<<<(E + 255) / 256, 256, 0, stream>>>(dst, E, deg);
    k_cnt<<<1, 128, 0, stream>>>(batch, N, cnt);
    k_packW<<<D * D / 256, 256, 0, stream>>>(W, Wp);
    k_scan1<<<nb_scan, 1024, 0, stream>>>(deg, N, rs, bsum);
    k_scan2<<<1, 1024, 0, stream>>>(bsum, nb_scan);
    k_scan3<<<nb_scan, 1024, 0, stream>>>(rs, cur, bsum, N);
    k_gemm<<<(N + 63) / 64, 256, 0, stream>>>(x, Wp, deg, h, N);
    k_fill<<<(E + 255) / 256, 256, 0, stream>>>(src, dst, E, cur, csr);
    k_gather<<<(N + 3) / 4, 256, 0, stream>>>(h, rs, deg, csr, batch, b, pa, pool, N);
    k_pool<<<NG * D / 256, 256, 0, stream>>>(pool, cnt, out);
}

// Round 3
// 307.098 us; speedup vs baseline: 1.6183x; 1.5033x over previous
//
#include <hip/hip_runtime.h>

#define D 128
#define NG 128
#define NBINS 64
#define EPB 8192      // edges per phase-A block
#define NB1MAX 512    // max coarse buckets (N/256)

typedef unsigned short ushort_t;
typedef __bf16 bf16x8 __attribute__((ext_vector_type(8)));
typedef float floatx4 __attribute__((ext_vector_type(4)));

static __device__ __forceinline__ unsigned short f2bf(float f) {
    unsigned u = __float_as_uint(f);
    unsigned r = (u + 0x7fffu + ((u >> 16) & 1u)) >> 16;  // RNE
    return (unsigned short)r;
}

// ---------- per-graph node counts via binary search (batch is sorted) ----------
__global__ __launch_bounds__(128) void k_cnt(const int* __restrict__ batch, int N, int* __restrict__ cnt) {
    int g = threadIdx.x;
    int lo = 0, hi = N;
    while (lo < hi) { int mid = (lo + hi) >> 1; if (batch[mid] < g) lo = mid + 1; else hi = mid; }
    int a = lo;
    hi = N;
    while (lo < hi) { int mid = (lo + hi) >> 1; if (batch[mid] < g + 1) lo = mid + 1; else hi = mid; }
    cnt[g] = lo - a;
}

// ---------- Phase A1: per-(bucket, block) histogram, LDS-aggregated ----------
__global__ __launch_bounds__(256) void k_ahist(const int* __restrict__ dst, int E, int nb1, int nblk,
                                               int* __restrict__ cnt1) {
    __shared__ int hist[NB1MAX];
    int tid = threadIdx.x;
    for (int b = tid; b < nb1; b += 256) hist[b] = 0;
    __syncthreads();
    int base = blockIdx.x * EPB;
    for (int k = tid; k < EPB; k += 256) {
        int i = base + k;
        if (i < E) atomicAdd(&hist[dst[i] >> 8], 1);
    }
    __syncthreads();
    for (int b = tid; b < nb1; b += 256) cnt1[b * nblk + blockIdx.x] = hist[b];
}

// ---------- 3-kernel exclusive scan (over cnt1, M = nb1*nblk elements) ----------
__global__ __launch_bounds__(1024) void k_scan1(const int* __restrict__ in, int M,
                                                int* __restrict__ outv, int* __restrict__ bsum) {
    __shared__ int s[1024];
    int tid = threadIdx.x;
    int i = blockIdx.x * 1024 + tid;
    int v = (i < M) ? in[i] : 0;
    s[tid] = v;
    __syncthreads();
    for (int off = 1; off < 1024; off <<= 1) {
        int t = (tid >= off) ? s[tid - off] : 0;
        __syncthreads();
        s[tid] += t;
        __syncthreads();
    }
    if (i < M) outv[i] = s[tid] - v;
    if (tid == 1023) bsum[blockIdx.x] = s[1023];
}

__global__ __launch_bounds__(1024) void k_scan2(int* __restrict__ bsum, int nb) {
    __shared__ int s[1024];
    int tid = threadIdx.x;
    int v = (tid < nb) ? bsum[tid] : 0;
    s[tid] = v;
    __syncthreads();
    for (int off = 1; off < 1024; off <<= 1) {
        int t = (tid >= off) ? s[tid - off] : 0;
        __syncthreads();
        s[tid] += t;
        __syncthreads();
    }
    if (tid < nb) bsum[tid] = s[tid] - v;
}

__global__ __launch_bounds__(1024) void k_scan3(int* __restrict__ outv, const int* __restrict__ bsum, int M) {
    int i = blockIdx.x * 1024 + threadIdx.x;
    if (i < M) outv[i] += bsum[blockIdx.x];
}

// ---------- Phase A2: scatter (src,dst) into bucket-contiguous segments via LDS cursors ----------
__global__ __launch_bounds__(256) void k_ascatter(const int* __restrict__ src, const int* __restrict__ dst, int E,
                                                  int nb1, int nblk, const int* __restrict__ off1,
                                                  int2* __restrict__ ebuf) {
    __shared__ int curs[NB1MAX];
    int tid = threadIdx.x;
    for (int b = tid; b < nb1; b += 256) curs[b] = off1[b * nblk + blockIdx.x];
    __syncthreads();
    int base = blockIdx.x * EPB;
    for (int k = tid; k < EPB; k += 256) {
        int i = base + k;
        if (i < E) {
            int d = dst[i];
            int pos = atomicAdd(&curs[d >> 8], 1);
            ebuf[pos] = make_int2(src[i], d);
        }
    }
}

// ---------- Phase B: per-bucket fine sort -> rs, deg, csr (all LDS atomics) ----------
__global__ __launch_bounds__(256) void k_bucket(const int2* __restrict__ ebuf, const int* __restrict__ off1,
                                                int E, int nb1, int nblk, int N,
                                                int* __restrict__ rs, int* __restrict__ deg,
                                                int* __restrict__ csr) {
    __shared__ int hist[256];
    __shared__ int sc[256];
    __shared__ int curs[256];
    int tid = threadIdx.x;
    int b = blockIdx.x;
    int s = off1[b * nblk];
    int e = (b + 1 < nb1) ? off1[(b + 1) * nblk] : E;
    int n0 = b << 8;

    hist[tid] = 0;
    __syncthreads();
    for (int i = s + tid; i < e; i += 256) atomicAdd(&hist[ebuf[i].y - n0], 1);
    __syncthreads();
    int v = hist[tid];
    sc[tid] = v;
    __syncthreads();
    for (int off = 1; off < 256; off <<= 1) {
        int t = (tid >= off) ? sc[tid - off] : 0;
        __syncthreads();
        sc[tid] += t;
        __syncthreads();
    }
    int excl = sc[tid] - v;
    int node = n0 + tid;
    if (node < N) {
        rs[node] = s + excl;
        deg[node] = v;
    }
    curs[tid] = s + excl;
    __syncthreads();
    for (int i = s + tid; i < e; i += 256) {
        int2 p = ebuf[i];
        int pos = atomicAdd(&curs[p.y - n0], 1);
        csr[pos] = p.x;
    }
}

// ---------- pack W: fp32 [k][c] -> bf16 col-major Wp[c][k] ----------
__global__ __launch_bounds__(256) void k_packW(const float* __restrict__ W, ushort_t* __restrict__ Wp) {
    int t = blockIdx.x * 256 + threadIdx.x;
    int c = t >> 7, k = t & 127;
    Wp[t] = f2bf(W[k * D + c]);
}

// ---------- MFMA GEMM: h[r][c] = bf16( dinv[r] * sum_k x[r][k]*W[k][c] ) ----------
__global__ __launch_bounds__(256) void k_gemm(const float* __restrict__ x, const ushort_t* __restrict__ Wp,
                                              const int* __restrict__ deg, ushort_t* __restrict__ h, int N) {
    __shared__ ushort_t hs[64][130];
    const int tid = threadIdx.x;
    const int w = tid >> 6;
    const int lane = tid & 63;
    const int q = lane >> 4;
    const int m = lane & 15;
    const int row0 = blockIdx.x * 64;
    const int arow = row0 + w * 16 + m;

    floatx4 acc[8];
#pragma unroll
    for (int nt = 0; nt < 8; ++nt) acc[nt] = (floatx4){0.f, 0.f, 0.f, 0.f};

    const bool rowok = (arow < N);
    const float* xrow = x + (size_t)arow * D;

#pragma unroll
    for (int kb = 0; kb < 4; ++kb) {
        union { bf16x8 v; ushort_t u[8]; } af;
        if (rowok) {
            float4 v0 = *(const float4*)&xrow[kb * 32 + q * 8];
            float4 v1 = *(const float4*)&xrow[kb * 32 + q * 8 + 4];
            af.u[0] = f2bf(v0.x); af.u[1] = f2bf(v0.y); af.u[2] = f2bf(v0.z); af.u[3] = f2bf(v0.w);
            af.u[4] = f2bf(v1.x); af.u[5] = f2bf(v1.y); af.u[6] = f2bf(v1.z); af.u[7] = f2bf(v1.w);
        } else {
#pragma unroll
            for (int j = 0; j < 8; ++j) af.u[j] = 0;
        }
#pragma unroll
        for (int nt = 0; nt < 8; ++nt) {
            int c = nt * 16 + m;
            const bf16x8 bf = *(const bf16x8*)(Wp + (size_t)c * D + kb * 32 + q * 8);
            acc[nt] = __builtin_amdgcn_mfma_f32_16x16x32_bf16(af.v, bf, acc[nt], 0, 0, 0);
        }
    }

    float di[4];
#pragma unroll
    for (int r = 0; r < 4; ++r) {
        int row = row0 + w * 16 + q * 4 + r;
        di[r] = (row < N) ? rsqrtf((float)(deg[row] + 1)) : 0.f;
    }
#pragma unroll
    for (int nt = 0; nt < 8; ++nt) {
        int c = nt * 16 + m;
#pragma unroll
        for (int r = 0; r < 4; ++r) {
            hs[w * 16 + q * 4 + r][c] = f2bf(acc[nt][r] * di[r]);
        }
    }
    __syncthreads();
#pragma unroll
    for (int it = 0; it < 8; ++it) {
        int f = it * 256 + tid;
        int r = f >> 5;
        int cq = f & 31;
        int row = row0 + r;
        if (row < N) {
            const ushort_t* p = &hs[r][cq * 4];
            uint2 vv;
            vv.x = (unsigned)p[0] | ((unsigned)p[1] << 16);
            vv.y = (unsigned)p[2] | ((unsigned)p[3] << 16);
            *(uint2*)&h[(size_t)row * D + cq * 4] = vv;
        }
    }
}

// ---------- gather + finalize: one wave per node, h in bf16 ----------
__global__ __launch_bounds__(256) void k_gather(const ushort_t* __restrict__ h, const int* __restrict__ rs,
                                                const int* __restrict__ deg, const int* __restrict__ csr,
                                                const int* __restrict__ batch, const float* __restrict__ b,
                                                const float* __restrict__ pa, float* __restrict__ pool, int N) {
    int node = (int)((blockIdx.x * (unsigned)blockDim.x + threadIdx.x) >> 6);
    int lane = threadIdx.x & 63;
    if (node >= N) return;

    unsigned sv = *(const unsigned*)&h[(size_t)node * D + lane * 2];
    float accx = __uint_as_float(sv << 16);
    float accy = __uint_as_float(sv & 0xffff0000u);

    int start = rs[node];
    int len = deg[node];
    for (int o = 0; o < len; o += 64) {
        int m = len - o;
        if (m > 64) m = 64;
        int idx = (o + lane < len) ? csr[start + o + lane] : 0;
        int j = 0;
        for (; j + 1 < m; j += 2) {
            int s0 = __shfl(idx, j);
            int s1 = __shfl(idx, j + 1);
            unsigned v0 = *(const unsigned*)&h[(size_t)s0 * D + lane * 2];
            unsigned v1 = *(const unsigned*)&h[(size_t)s1 * D + lane * 2];
            accx += __uint_as_float(v0 << 16);
            accy += __uint_as_float(v0 & 0xffff0000u);
            accx += __uint_as_float(v1 << 16);
            accy += __uint_as_float(v1 & 0xffff0000u);
        }
        if (j < m) {
            int s0 = __shfl(idx, j);
            unsigned v0 = *(const unsigned*)&h[(size_t)s0 * D + lane * 2];
            accx += __uint_as_float(v0 << 16);
            accy += __uint_as_float(v0 & 0xffff0000u);
        }
    }
    float dinv = rsqrtf((float)(len + 1));
    float2 bb = *(const float2*)&b[lane * 2];
    float2 aa = *(const float2*)&pa[lane * 2];
    float vx = accx * dinv + bb.x;
    float vy = accy * dinv + bb.y;
    vx = vx > 0.f ? vx : aa.x * vx;
    vy = vy > 0.f ? vy : aa.y * vy;
    float ss = vx * vx + vy * vy;
#pragma unroll
    for (int o = 32; o > 0; o >>= 1) ss += __shfl_xor(ss, o);
    float inv = 1.0f / fmaxf(sqrtf(ss), 1e-12f);
    vx *= inv;
    vy *= inv;
    int g = batch[node];
    float* p = pool + (size_t)(blockIdx.x & (NBINS - 1)) * (NG * D) + (size_t)g * D + lane * 2;
    atomicAdd(p, vx);
    atomicAdd(p + 1, vy);
}

// ---------- pool reduction ----------
__global__ __launch_bounds__(256) void k_pool(const float* __restrict__ pool, const int* __restrict__ cnt,
                                              float* __restrict__ out) {
    int idx = blockIdx.x * 256 + threadIdx.x;
    float s = 0.f;
    for (int bin = 0; bin < NBINS; ++bin) s += pool[(size_t)bin * NG * D + idx];
    out[idx] = s / fmaxf((float)cnt[idx >> 7], 1.0f);
}

extern "C" void kernel_launch(void* const* d_in, const int* in_sizes, int n_in,
                              void* d_out, int out_size, void* d_ws, size_t ws_size,
                              hipStream_t stream) {
    const float* x = (const float*)d_in[0];
    const int* ei = (const int*)d_in[1];
    const int* batch = (const int*)d_in[2];
    const float* W = (const float*)d_in[3];
    const float* b = (const float*)d_in[4];
    const float* pa = (const float*)d_in[5];
    float* out = (float*)d_out;

    const int N = in_sizes[0] / D;
    const int E = in_sizes[1] / 2;
    const int* src = ei;
    const int* dst = ei + E;

    const int nb1 = (N + 255) >> 8;            // coarse buckets (256 nodes each)
    const int nblk = (E + EPB - 1) / EPB;      // phase-A blocks
    const int M = nb1 * nblk;                  // cnt1 elements
    const int nb_scan = (M + 1023) / 1024;

    char* w = (char*)d_ws;
    auto carve = [&](size_t bytes) {
        void* p = (void*)w;
        w += (bytes + 255) & ~(size_t)255;
        return p;
    };
    ushort_t* h = (ushort_t*)carve((size_t)N * D * sizeof(ushort_t));   // 25.6 MB
    ushort_t* Wp = (ushort_t*)carve((size_t)D * D * sizeof(ushort_t));
    int* deg = (int*)carve((size_t)N * sizeof(int));
    int* rs = (int*)carve((size_t)N * sizeof(int));
    int* csr = (int*)carve((size_t)E * sizeof(int));                    // 6.4 MB
    int* cnt1 = (int*)carve((size_t)M * sizeof(int));
    int2* ebuf = (int2*)carve((size_t)E * sizeof(int2));                // 12.8 MB
    int* bsum = (int*)carve(1024 * sizeof(int));
    int* cnt = (int*)carve(NG * sizeof(int));
    float* pool = (float*)carve((size_t)NBINS * NG * D * sizeof(float));

    hipMemsetAsync(pool, 0, (size_t)NBINS * NG * D * sizeof(float), stream);

    k_cnt<<<1, 128, 0, stream>>>(batch, N, cnt);
    k_packW<<<D * D / 256, 256, 0, stream>>>(W, Wp);
    k_ahist<<<nblk, 256, 0, stream>>>(dst, E, nb1, nblk, cnt1);
    k_scan1<<<nb_scan, 1024, 0, stream>>>(cnt1, M, cnt1, bsum);   // in-place exclusive scan
    k_scan2<<<1, 1024, 0, stream>>>(bsum, nb_scan);
    k_scan3<<<nb_scan, 1024, 0, stream>>>(cnt1, bsum, M);
    k_ascatter<<<nblk, 256, 0, stream>>>(src, dst, E, nb1, nblk, cnt1, ebuf);
    k_bucket<<<nb1, 256, 0, stream>>>(ebuf, cnt1, E, nb1, nblk, N, rs, deg, csr);
    k_gemm<<<(N + 63) / 64, 256, 0, stream>>>(x, Wp, deg, h, N);
    k_gather<<<(N + 3) / 4, 256, 0, stream>>>(h, rs, deg, csr, batch, b, pa, pool, N);
    k_pool<<<NG * D / 256, 256, 0, stream>>>(pool, cnt, out);
}